// Round 1
// baseline (39.948 us; speedup 1.0000x reference)
//
#include <hip/hip_runtime.h>

#define BB 2
#define SS 4096
#define DD 64
#define HH 8
#define TB 256
#define NBLK (SS / TB)   // 16

struct Partial { double maxv; double minv; int maxi; int mini; };

// K1: each block handles 256 rows (t) of one batch; computes k=x·ks[h] and
// q=x·qs[h] in double, writes q-sign bytes and per-block argmax/argmin partials.
__global__ void __launch_bounds__(TB) k_dots(
    const float* __restrict__ x,        // [B,S,D]
    const float* __restrict__ qs,       // [H,1,D]
    const float* __restrict__ ks,       // [H,1,D]
    Partial* __restrict__ partials,     // [B*H][NBLK]
    signed char* __restrict__ qsign)    // [B*H][S]
{
    const int tid  = threadIdx.x;
    const int blk  = blockIdx.x;        // 0 .. B*NBLK-1
    const int b    = blk / NBLK;
    const int tb   = blk % NBLK;
    const int t    = tb * TB + tid;

    __shared__ float s_qs[HH * DD];
    __shared__ float s_ks[HH * DD];
    for (int i = tid; i < HH * DD; i += TB) {
        s_qs[i] = qs[i];
        s_ks[i] = ks[i];
    }
    __syncthreads();

    // load this thread's x row into registers
    float xr[DD];
    const float4* xp = (const float4*)(x + ((size_t)b * SS + t) * DD);
#pragma unroll
    for (int i = 0; i < DD / 4; ++i) {
        float4 v = xp[i];
        xr[4*i+0] = v.x; xr[4*i+1] = v.y; xr[4*i+2] = v.z; xr[4*i+3] = v.w;
    }

    __shared__ double rvmax[TB], rvmin[TB];
    __shared__ int    rimax[TB], rimin[TB];

    for (int h = 0; h < HH; ++h) {
        double qd = 0.0, kd = 0.0;
#pragma unroll
        for (int i = 0; i < DD; ++i) {
            qd += (double)xr[i] * (double)s_qs[h * DD + i];
            kd += (double)xr[i] * (double)s_ks[h * DD + i];
        }
        qsign[((size_t)b * HH + h) * SS + t] =
            (qd > 0.0) ? (signed char)1 : (qd < 0.0 ? (signed char)-1 : (signed char)0);

        rvmax[tid] = kd; rimax[tid] = t;
        rvmin[tid] = kd; rimin[tid] = t;
        __syncthreads();
        for (int ofs = TB / 2; ofs > 0; ofs >>= 1) {
            if (tid < ofs) {
                double v2 = rvmax[tid + ofs]; int i2 = rimax[tid + ofs];
                // prefer larger value; on tie prefer smaller index (first occurrence)
                if (v2 > rvmax[tid] || (v2 == rvmax[tid] && i2 < rimax[tid])) {
                    rvmax[tid] = v2; rimax[tid] = i2;
                }
                double v3 = rvmin[tid + ofs]; int i3 = rimin[tid + ofs];
                if (v3 < rvmin[tid] || (v3 == rvmin[tid] && i3 < rimin[tid])) {
                    rvmin[tid] = v3; rimin[tid] = i3;
                }
            }
            __syncthreads();
        }
        if (tid == 0) {
            Partial p;
            p.maxv = rvmax[0]; p.maxi = rimax[0];
            p.minv = rvmin[0]; p.mini = rimin[0];
            partials[((size_t)b * HH + h) * NBLK + tb] = p;
        }
        __syncthreads();
    }
}

// K2: one thread per (b,h), scan NBLK partials in order -> tmax/tmin indices.
__global__ void k_finalize(const Partial* __restrict__ partials,
                           int* __restrict__ tmax, int* __restrict__ tmin)
{
    int i = threadIdx.x;
    if (i >= BB * HH) return;
    const Partial* p = partials + (size_t)i * NBLK;
    double bmax = p[0].maxv; int imax = p[0].maxi;
    double bmin = p[0].minv; int imin = p[0].mini;
    for (int j = 1; j < NBLK; ++j) {
        if (p[j].maxv > bmax) { bmax = p[j].maxv; imax = p[j].maxi; }  // strict: keeps first
        if (p[j].minv < bmin) { bmin = p[j].minv; imin = p[j].mini; }
    }
    tmax[i] = imax;
    tmin[i] = imin;
}

// K3: one wave (64 lanes) per output row [b,s]; lane = d.
// Gather the 8 selected rows, sum, L2-normalize.
__global__ void __launch_bounds__(256) k_out(
    const float* __restrict__ x,
    const signed char* __restrict__ qsign,
    const int* __restrict__ tmax, const int* __restrict__ tmin,
    float* __restrict__ out)
{
    const int wid  = threadIdx.x >> 6;
    const int lane = threadIdx.x & 63;
    const int row  = blockIdx.x * 4 + wid;   // 0 .. B*S-1
    const int b    = row / SS;
    const int s    = row % SS;

    float acc = 0.f;
#pragma unroll
    for (int h = 0; h < HH; ++h) {
        const int bh = b * HH + h;
        const int sg = qsign[(size_t)bh * SS + s];
        const int idx = (sg > 0) ? tmax[bh] : (sg < 0 ? tmin[bh] : 0);
        acc += x[((size_t)b * SS + idx) * DD + lane];
    }

    double sq = (double)acc * (double)acc;
#pragma unroll
    for (int o = 32; o > 0; o >>= 1) sq += __shfl_xor(sq, o, 64);
    float nrm = (float)sqrt(sq);

    out[((size_t)b * SS + s) * DD + lane] = acc / nrm;
}

extern "C" void kernel_launch(void* const* d_in, const int* in_sizes, int n_in,
                              void* d_out, int out_size, void* d_ws, size_t ws_size,
                              hipStream_t stream)
{
    const float* x  = (const float*)d_in[0];
    const float* qs = (const float*)d_in[1];
    const float* ks = (const float*)d_in[2];
    float* out = (float*)d_out;

    char* ws = (char*)d_ws;
    Partial* partials  = (Partial*)ws;                       // 256 * 24 B = 6144 B
    int* tmax          = (int*)(ws + 8192);                  // 16 ints
    int* tmin          = tmax + BB * HH;                     // 16 ints
    signed char* qsign = (signed char*)(ws + 8192 + 256);    // 65536 B

    k_dots<<<BB * NBLK, TB, 0, stream>>>(x, qs, ks, partials, qsign);
    k_finalize<<<1, 64, 0, stream>>>(partials, tmax, tmin);
    k_out<<<(BB * SS) / 4, 256, 0, stream>>>(x, qsign, tmax, tmin, out);
}

// Round 2
// 30.133 us; speedup vs baseline: 1.3257x; 1.3257x over previous
//
#include <hip/hip_runtime.h>

#define BB 2
#define SS 4096
#define DD 64
#define HH 8
#define NCH 16           // chunks per batch (256 rows each)
#define TB 256

struct Partial { double maxv, minv; int maxi, mini; };

// K1: block = (batch, 256-row chunk). Each thread owns one row t: computes
// q=x_t·qs[h], k=x_t·ks[h] in double for all 8 heads, writes sign(q) bytes,
// and reduces (k, t) argmax/argmin per head via wave shuffles (2 barriers total).
__global__ void __launch_bounds__(TB) k_scan(
    const float* __restrict__ x,        // [B,S,D]
    const float* __restrict__ qs,       // [H,1,D]
    const float* __restrict__ ks,       // [H,1,D]
    Partial* __restrict__ partials,     // [B*H][NCH]
    signed char* __restrict__ qsign)    // [B*H][S]
{
    const int tid  = threadIdx.x;
    const int b    = blockIdx.x / NCH;
    const int ch   = blockIdx.x % NCH;
    const int t    = ch * TB + tid;
    const int lane = tid & 63;
    const int wid  = tid >> 6;

    __shared__ float s_qs[HH * DD];
    __shared__ float s_ks[HH * DD];
    for (int i = tid; i < HH * DD; i += TB) { s_qs[i] = qs[i]; s_ks[i] = ks[i]; }
    __syncthreads();

    float xr[DD];
    const float4* xp = (const float4*)(x + ((size_t)b * SS + t) * DD);
#pragma unroll
    for (int i = 0; i < DD / 4; ++i) {
        float4 v = xp[i];
        xr[4*i+0] = v.x; xr[4*i+1] = v.y; xr[4*i+2] = v.z; xr[4*i+3] = v.w;
    }

    __shared__ double s_maxv[HH][4]; __shared__ int s_maxi[HH][4];
    __shared__ double s_minv[HH][4]; __shared__ int s_mini[HH][4];

#pragma unroll
    for (int h = 0; h < HH; ++h) {
        double q0 = 0, q1 = 0, k0 = 0, k1 = 0;
#pragma unroll
        for (int i = 0; i < DD; i += 2) {
            q0 += (double)xr[i]   * (double)s_qs[h*DD + i];
            q1 += (double)xr[i+1] * (double)s_qs[h*DD + i + 1];
            k0 += (double)xr[i]   * (double)s_ks[h*DD + i];
            k1 += (double)xr[i+1] * (double)s_ks[h*DD + i + 1];
        }
        const double qd = q0 + q1, kd = k0 + k1;
        qsign[((size_t)b*HH + h)*SS + t] =
            (qd > 0.0) ? (signed char)1 : (qd < 0.0 ? (signed char)-1 : (signed char)0);

        // wave-level (value,index) argmax & argmin, first-occurrence tie-break
        double mv = kd, nv = kd; int mi = t, ni = t;
#pragma unroll
        for (int o = 1; o < 64; o <<= 1) {
            double mv2 = __shfl_xor(mv, o, 64); int mi2 = __shfl_xor(mi, o, 64);
            if (mv2 > mv || (mv2 == mv && mi2 < mi)) { mv = mv2; mi = mi2; }
            double nv2 = __shfl_xor(nv, o, 64); int ni2 = __shfl_xor(ni, o, 64);
            if (nv2 < nv || (nv2 == nv && ni2 < ni)) { nv = nv2; ni = ni2; }
        }
        if (lane == 0) {
            s_maxv[h][wid] = mv; s_maxi[h][wid] = mi;
            s_minv[h][wid] = nv; s_mini[h][wid] = ni;
        }
    }
    __syncthreads();

    if (tid < HH) {
        const int h = tid;
        double mv = s_maxv[h][0]; int mi = s_maxi[h][0];
        double nv = s_minv[h][0]; int ni = s_mini[h][0];
#pragma unroll
        for (int w = 1; w < 4; ++w) {
            if (s_maxv[h][w] > mv)       { mv = s_maxv[h][w]; mi = s_maxi[h][w]; }
            else if (s_maxv[h][w] == mv && s_maxi[h][w] < mi) { mi = s_maxi[h][w]; }
            if (s_minv[h][w] < nv)       { nv = s_minv[h][w]; ni = s_mini[h][w]; }
            else if (s_minv[h][w] == nv && s_mini[h][w] < ni) { ni = s_mini[h][w]; }
        }
        Partial p; p.maxv = mv; p.minv = nv; p.maxi = mi; p.mini = ni;
        partials[((size_t)b*HH + h)*NCH + ch] = p;
    }
}

// K2: absorbs finalize (each block redundantly combines the 256 partials,
// L2-hot) then one wave per output row: gather 8 selected rows, sum, normalize.
__global__ void __launch_bounds__(TB) k_out(
    const float* __restrict__ x,
    const signed char* __restrict__ qsign,
    const Partial* __restrict__ partials,
    float* __restrict__ out)
{
    __shared__ int s_tmax[BB*HH], s_tmin[BB*HH];
    const int tid = threadIdx.x;

    if (tid < BB*HH) {
        const Partial* p = partials + (size_t)tid * NCH;
        double mv = p[0].maxv; int mi = p[0].maxi;
        double nv = p[0].minv; int ni = p[0].mini;
#pragma unroll
        for (int j = 1; j < NCH; ++j) {
            Partial q = p[j];
            if (q.maxv > mv) { mv = q.maxv; mi = q.maxi; }   // chunks ascend: strict keeps first
            if (q.minv < nv) { nv = q.minv; ni = q.mini; }
        }
        s_tmax[tid] = mi; s_tmin[tid] = ni;
    }
    __syncthreads();

    const int wid  = tid >> 6;
    const int lane = tid & 63;
    const int row  = blockIdx.x * 4 + wid;     // 0 .. B*S-1
    const int b    = row >> 12;                // /SS
    const int s    = row & (SS - 1);

    float acc = 0.f;
#pragma unroll
    for (int h = 0; h < HH; ++h) {
        const int bh = b*HH + h;
        const int sg = qsign[(size_t)bh*SS + s];
        const int idx = (sg > 0) ? s_tmax[bh] : (sg < 0 ? s_tmin[bh] : 0);
        acc += x[((size_t)b*SS + idx)*DD + lane];
    }

    float sq = acc * acc;
#pragma unroll
    for (int o = 1; o < 64; o <<= 1) sq += __shfl_xor(sq, o, 64);

    out[((size_t)b*SS + s)*DD + lane] = acc / sqrtf(sq);
}

extern "C" void kernel_launch(void* const* d_in, const int* in_sizes, int n_in,
                              void* d_out, int out_size, void* d_ws, size_t ws_size,
                              hipStream_t stream)
{
    const float* x  = (const float*)d_in[0];
    const float* qs = (const float*)d_in[1];
    const float* ks = (const float*)d_in[2];
    float* out = (float*)d_out;

    char* ws = (char*)d_ws;
    Partial* partials  = (Partial*)ws;                 // 256 * 24 B
    signed char* qsign = (signed char*)(ws + 8192);    // 64 KiB

    k_scan<<<BB * NCH, TB, 0, stream>>>(x, qs, ks, partials, qsign);
    k_out<<<(BB * SS) / 4, TB, 0, stream>>>(x, qsign, partials, out);
}

// Round 3
// 19.020 us; speedup vs baseline: 2.1003x; 1.5842x over previous
//
#include <hip/hip_runtime.h>

#define BB 2
#define SS 4096
#define DD 64
#define HH 8
#define TB 256
#define NCH (SS / TB)   // 16 chunks of 256 rows

struct Partial { float maxv, minv; int maxi, mini; };

// K1: block = (b, chunk, head). Each thread owns one row t for ONE head:
// fp32 dots q=x_t·qs[h], k=x_t·ks[h]; fp64 fallback only when |q|<=1e-4
// (sign-ambiguous zone; identical decisions to the all-double kernel).
// Wave-level (val,idx) argmax/argmin shuffles, 2 barriers total.
__global__ void __launch_bounds__(TB) k_scan(
    const float* __restrict__ x,        // [B,S,D]
    const float* __restrict__ qs,       // [H,1,D]
    const float* __restrict__ ks,       // [H,1,D]
    Partial* __restrict__ partials,     // [B*H][NCH]
    signed char* __restrict__ qsign)    // [B*H][S]
{
    const int tid  = threadIdx.x;
    const int h    = blockIdx.x & (HH - 1);
    const int ch   = (blockIdx.x >> 3) & (NCH - 1);
    const int b    = blockIdx.x >> 7;
    const int t    = ch * TB + tid;
    const int lane = tid & 63;
    const int wid  = tid >> 6;

    __shared__ float s_q[DD], s_k[DD];
    if (tid < DD) { s_q[tid] = qs[h*DD + tid]; s_k[tid] = ks[h*DD + tid]; }
    __syncthreads();

    float xr[DD];
    const float4* xp = (const float4*)(x + ((size_t)b * SS + t) * DD);
#pragma unroll
    for (int i = 0; i < DD / 4; ++i) {
        float4 v = xp[i];
        xr[4*i+0] = v.x; xr[4*i+1] = v.y; xr[4*i+2] = v.z; xr[4*i+3] = v.w;
    }

    float q0=0,q1=0,q2=0,q3=0, k0=0,k1=0,k2=0,k3=0;
#pragma unroll
    for (int i = 0; i < DD; i += 4) {
        q0 += xr[i+0]*s_q[i+0];  k0 += xr[i+0]*s_k[i+0];
        q1 += xr[i+1]*s_q[i+1];  k1 += xr[i+1]*s_k[i+1];
        q2 += xr[i+2]*s_q[i+2];  k2 += xr[i+2]*s_k[i+2];
        q3 += xr[i+3]*s_q[i+3];  k3 += xr[i+3]*s_k[i+3];
    }
    const float qf = (q0+q1)+(q2+q3);
    const float kf = (k0+k1)+(k2+k3);

    signed char sg;
    if (fabsf(qf) > 1e-4f) {
        sg = (qf > 0.f) ? (signed char)1 : (signed char)-1;
    } else {
        // rare (~1e-4 of rows): exact-sign fp64 recompute, same order as R2 kernel
        double a0 = 0.0, a1 = 0.0;
#pragma unroll
        for (int i = 0; i < DD; i += 2) {
            a0 += (double)xr[i]   * (double)s_q[i];
            a1 += (double)xr[i+1] * (double)s_q[i+1];
        }
        const double qd = a0 + a1;
        sg = (qd > 0.0) ? (signed char)1 : (qd < 0.0 ? (signed char)-1 : (signed char)0);
    }
    qsign[((size_t)b*HH + h)*SS + t] = sg;

    // wave-level (value,index) argmax & argmin, first-occurrence tie-break
    float mv = kf, nv = kf; int mi = t, ni = t;
#pragma unroll
    for (int o = 1; o < 64; o <<= 1) {
        float mv2 = __shfl_xor(mv, o, 64); int mi2 = __shfl_xor(mi, o, 64);
        if (mv2 > mv || (mv2 == mv && mi2 < mi)) { mv = mv2; mi = mi2; }
        float nv2 = __shfl_xor(nv, o, 64); int ni2 = __shfl_xor(ni, o, 64);
        if (nv2 < nv || (nv2 == nv && ni2 < ni)) { nv = nv2; ni = ni2; }
    }

    __shared__ float s_mv[4], s_nv[4];
    __shared__ int   s_mi[4], s_ni[4];
    if (lane == 0) { s_mv[wid] = mv; s_mi[wid] = mi; s_nv[wid] = nv; s_ni[wid] = ni; }
    __syncthreads();

    if (tid == 0) {
        float bmv = s_mv[0], bnv = s_nv[0]; int bmi = s_mi[0], bni = s_ni[0];
#pragma unroll
        for (int w = 1; w < 4; ++w) {   // waves ascend in t: strict compare keeps first
            if (s_mv[w] > bmv) { bmv = s_mv[w]; bmi = s_mi[w]; }
            if (s_nv[w] < bnv) { bnv = s_nv[w]; bni = s_ni[w]; }
        }
        Partial p; p.maxv = bmv; p.minv = bnv; p.maxi = bmi; p.mini = bni;
        partials[((size_t)b*HH + h)*NCH + ch] = p;
    }
}

// K2: each block redundantly folds the 256 partials (L2-hot, 4 KB), then
// one wave per output row: gather 8 selected rows, sum, L2-normalize.
__global__ void __launch_bounds__(TB) k_out(
    const float* __restrict__ x,
    const signed char* __restrict__ qsign,
    const Partial* __restrict__ partials,
    float* __restrict__ out)
{
    __shared__ int s_tmax[BB*HH], s_tmin[BB*HH];
    const int tid = threadIdx.x;

    if (tid < BB*HH) {
        const Partial* p = partials + (size_t)tid * NCH;
        float mv = p[0].maxv, nv = p[0].minv; int mi = p[0].maxi, ni = p[0].mini;
#pragma unroll
        for (int j = 1; j < NCH; ++j) {
            Partial q = p[j];
            if (q.maxv > mv) { mv = q.maxv; mi = q.maxi; }  // chunks ascend: strict keeps first
            if (q.minv < nv) { nv = q.minv; ni = q.mini; }
        }
        s_tmax[tid] = mi; s_tmin[tid] = ni;
    }
    __syncthreads();

    const int wid  = tid >> 6;
    const int lane = tid & 63;
    const int row  = blockIdx.x * 4 + wid;     // 0 .. B*S-1
    const int b    = row >> 12;                // / SS
    const int s    = row & (SS - 1);

    float acc = 0.f;
#pragma unroll
    for (int h = 0; h < HH; ++h) {
        const int bh = b*HH + h;
        const int sg = qsign[(size_t)bh*SS + s];
        const int idx = (sg > 0) ? s_tmax[bh] : (sg < 0 ? s_tmin[bh] : 0);
        acc += x[((size_t)b*SS + idx)*DD + lane];
    }

    float sq = acc * acc;
#pragma unroll
    for (int o = 1; o < 64; o <<= 1) sq += __shfl_xor(sq, o, 64);

    out[((size_t)b*SS + s)*DD + lane] = acc / sqrtf(sq);
}

extern "C" void kernel_launch(void* const* d_in, const int* in_sizes, int n_in,
                              void* d_out, int out_size, void* d_ws, size_t ws_size,
                              hipStream_t stream)
{
    const float* x  = (const float*)d_in[0];
    const float* qs = (const float*)d_in[1];
    const float* ks = (const float*)d_in[2];
    float* out = (float*)d_out;

    char* ws = (char*)d_ws;
    Partial* partials  = (Partial*)ws;                 // 256 * 16 B = 4 KiB
    signed char* qsign = (signed char*)(ws + 8192);    // 64 KiB

    k_scan<<<BB * NCH * HH, TB, 0, stream>>>(x, qs, ks, partials, qsign);
    k_out<<<(BB * SS) / 4, TB, 0, stream>>>(x, qsign, partials, out);
}